// Round 11
// baseline (572.479 us; speedup 1.0000x reference)
//
#include <hip/hip_runtime.h>
#include <math.h>

constexpr int NB = 16;
constexpr int NC = 128;
constexpr int NS = 2048;          // Np1 == Mp1 == S
constexpr float F_INV_TEMP = 100.0f;
constexpr float F_EPS = 1e-5f;
constexpr float NEGBIG = -1e30f;
constexpr int CHA = 4;            // stats m-chunks (512 each)
constexpr int CHB = 2;            // pass-B m-chunks (1024 each; ==2 keeps atomic merge deterministic)

typedef __attribute__((ext_vector_type(8))) _Float16 f16x8;
typedef __attribute__((ext_vector_type(4))) _Float16 f16x4;
typedef __attribute__((ext_vector_type(4))) float f32x4;

#define MFMA16(a, b, c) __builtin_amdgcn_mfma_f32_16x16x32_f16((a), (b), (c), 0, 0, 0)
#define GLOAD_LDS(g, l) __builtin_amdgcn_global_load_lds(                      \
    (const __attribute__((address_space(1))) void*)(g),                       \
    (__attribute__((address_space(3))) void*)(l), 16, 0, 0)
#define SBAR()   __builtin_amdgcn_s_barrier()
#define WAITV(N) asm volatile("s_waitcnt vmcnt(" #N ")" ::: "memory")
#define SCHED0() __builtin_amdgcn_sched_barrier(0)

// ---- workspace layout (float offsets) ----
constexpr size_t RM_OFF = 64;                        // rowmax [NB*NS]
constexpr size_t RI_OFF = RM_OFF + (size_t)NB * NS;  // rowinv [NB*NS]
constexpr size_t PM_OFF = RI_OFF + (size_t)NB * NS;  // partial max [NB*NS][CHA]
constexpr size_t PS_OFF = PM_OFF + (size_t)NB * NS * CHA;
constexpr size_t F16_OFF = PS_OFF + (size_t)NB * NS * CHA;
// fp16 region (element offsets):
constexpr size_t QT_H   = 0;                                  // q [b][s][c]
constexpr size_t KT_H   = QT_H + (size_t)NB * NS * NC;        // k [b][s][c]
constexpr size_t VT_H   = KT_H + (size_t)NB * NS * NC;        // v [b][c][s]
constexpr size_t W16_H  = VT_H + (size_t)NB * NS * NC;        // W16 [3][128][128]

// ---------------- K0: ragged lengths ----------------
__global__ void k_lens(const int* __restrict__ lm_t, const int* __restrict__ lm_r,
                       int* __restrict__ lens) {
    int b = blockIdx.x & 15;
    const int* src = (blockIdx.x < 16) ? lm_t : lm_r;
    src += b * 4096;
    int m = 0;
    for (int i = threadIdx.x; i < 4096; i += 256) m = max(m, src[i]);
    for (int off = 32; off; off >>= 1) m = max(m, __shfl_down(m, off, 64));
    __shared__ int red[4];
    if ((threadIdx.x & 63) == 0) red[threadIdx.x >> 6] = m;
    __syncthreads();
    if (threadIdx.x == 0) {
        m = max(max(red[0], red[1]), max(red[2], red[3]));
        lens[blockIdx.x] = m + 1;   // [0..15]=len_t, [16..31]=len_r
    }
}

// ---------------- K0b: convert W to fp16 ----------------
__global__ void k_prep(const float* __restrict__ Wq, const float* __restrict__ Wk,
                       const float* __restrict__ Wv, _Float16* __restrict__ W16) {
    int i = blockIdx.x * 256 + threadIdx.x;
    W16[i]               = (_Float16)Wq[i];
    W16[i + NC * NC]     = (_Float16)Wk[i];
    W16[i + 2 * NC * NC] = (_Float16)Wv[i];
}

// ---------------- K1: fused center-norm + projection GEMM (MFMA) ----------------
// MODE 0/1: out [b][s][c] fp16 (q,k); MODE 2: vout [b][c][s] fp16 (v)
template <bool NORM, int MODE>
__global__ __launch_bounds__(256) void k_qkv(const float* __restrict__ x,
                                             const _Float16* __restrict__ W16,
                                             const float* __restrict__ bias,
                                             _Float16* __restrict__ out,
                                             _Float16* __restrict__ vout) {
    __shared__ __align__(16) char smem[48 * 1024];
    float*    xs = (float*)smem;                        // [128][64] fp32 (32 KB)
    _Float16* xn = (_Float16*)(smem + 32 * 1024);       // [64][16 slots of 8] swizzled (16 KB)
    _Float16 (*Vt)[72] = (_Float16 (*)[72])smem;        // MODE2: [128][72] aliases xs
    __shared__ float ps[4][64], pq[4][64], cmean[64], cscale[64];

    const int b  = blockIdx.y;
    const int s0 = blockIdx.x * 64;
    const float* xb = x + (size_t)b * NC * NS + s0;

    for (int idx = threadIdx.x; idx < NC * 16; idx += 256) {
        int c = idx >> 4, j = (idx & 15) << 2;
        *(float4*)&xs[c * 64 + j] = *(const float4*)&xb[(size_t)c * NS + j];
    }
    __syncthreads();

    if (NORM) {
        int j = threadIdx.x & 63, p = threadIdx.x >> 6;
        float sum = 0.f, ssq = 0.f;
#pragma unroll
        for (int cc = 0; cc < 32; ++cc) {
            float v = xs[(p * 32 + cc) * 64 + j];
            sum += v; ssq += v * v;
        }
        ps[p][j] = sum; pq[p][j] = ssq;
        __syncthreads();
        if (threadIdx.x < 64) {
            float sm = ps[0][j] + ps[1][j] + ps[2][j] + ps[3][j];
            float sq = pq[0][j] + pq[1][j] + pq[2][j] + pq[3][j];
            float mean = sm * (1.f / NC);
            float var = sq - (float)NC * mean * mean;
            cmean[j]  = mean;
            cscale[j] = 1.f / (sqrtf(fmaxf(var, 0.f)) + F_EPS);
        }
        __syncthreads();
    }

    {
        const int lane = threadIdx.x & 63;           // s
        const int w4   = threadIdx.x >> 6;           // c chunk of 32
        const float mn = NORM ? cmean[lane] : 0.f;
        const float sc = NORM ? cscale[lane] : 1.f;
#pragma unroll
        for (int q = 0; q < 4; ++q) {
            f16x8 v8;
#pragma unroll
            for (int i = 0; i < 8; ++i)
                v8[i] = (_Float16)((xs[(w4 * 32 + q * 8 + i) * 64 + lane] - mn) * sc);
            *(f16x8*)(xn + lane * 128 + (((w4 * 4 + q) ^ (lane & 7)) << 3)) = v8;
        }
    }
    __syncthreads();   // xn ready; xs dead (Vt may alias it)

    const int w = threadIdx.x >> 6, lane = threadIdx.x & 63;
    const int ln = lane & 15, g = lane >> 4;
    const int sl = w * 16 + ln;                      // local s row (0..63)

    f16x8 xf[4];
#pragma unroll
    for (int jj = 0; jj < 4; ++jj)
        xf[jj] = *(const f16x8*)(xn + sl * 128 + (((jj * 4 + g) ^ (ln & 7)) << 3));

#pragma unroll
    for (int ot = 0; ot < 8; ++ot) {
        const _Float16* wrow = W16 + (size_t)(ot * 16 + ln) * NC + g * 8;
        f32x4 acc = {0.f, 0.f, 0.f, 0.f};
        acc = MFMA16(*(const f16x8*)(wrow),      xf[0], acc);
        acc = MFMA16(*(const f16x8*)(wrow + 32), xf[1], acc);
        acc = MFMA16(*(const f16x8*)(wrow + 64), xf[2], acc);
        acc = MFMA16(*(const f16x8*)(wrow + 96), xf[3], acc);
        const float4 bv = *(const float4*)&bias[ot * 16 + 4 * g];
        f16x4 res;
        res[0] = (_Float16)(acc[0] + bv.x);
        res[1] = (_Float16)(acc[1] + bv.y);
        res[2] = (_Float16)(acc[2] + bv.z);
        res[3] = (_Float16)(acc[3] + bv.w);
        if (MODE < 2) {
            *(f16x4*)(out + ((size_t)b * NS + s0 + sl) * NC + ot * 16 + 4 * g) = res;
        } else {
#pragma unroll
            for (int r = 0; r < 4; ++r)
                Vt[ot * 16 + 4 * g + r][sl] = res[r];
        }
    }
    if (MODE == 2) {
        __syncthreads();
        int o = threadIdx.x >> 1, sh = threadIdx.x & 1;
        _Float16* vr = vout + ((size_t)b * NC + o) * NS + s0 + sh * 32;
        const _Float16* src = &Vt[o][sh * 32];
#pragma unroll
        for (int i = 0; i < 4; ++i) *(f16x8*)(vr + i * 8) = *(const f16x8*)(src + i * 8);
    }
}

// ---------------- K3: partial softmax stats (split-m, async pipeline) ----------------
__global__ __launch_bounds__(512, 8) void k_stats(const _Float16* __restrict__ qt,
                                                  const _Float16* __restrict__ kt,
                                                  const int* __restrict__ lens,
                                                  float* __restrict__ pM,
                                                  float* __restrict__ pS) {
    __shared__ __align__(16) _Float16 Kl[2][64 * 128];
    const int nt = blockIdx.x, ch = blockIdx.y, b = blockIdx.z;
    const int tid = threadIdx.x;
    const int w = tid >> 6, lane = tid & 63, ln = lane & 15, g = lane >> 4;
    const int n_base = nt * 128 + w * 16;
    const int lenr = lens[16 + b];
    const int swz = ln & 7;

    const _Float16* qrow = qt + ((size_t)b * NS + n_base + ln) * NC + g * 8;
    f16x8 qf[4];
#pragma unroll
    for (int j = 0; j < 4; ++j) qf[j] = *(const f16x8*)(qrow + 32 * j);

    const _Float16* kb = kt + (size_t)b * NS * NC;

    size_t goffk[2];
#pragma unroll
    for (int q = 0; q < 2; ++q) {
        const int ck = w * 2 + q;
        const int r  = ck * 4 + (lane >> 4);
        const int j  = lane & 15;
        goffk[q] = (size_t)r * NC + ((j ^ (r & 7)) << 3);
    }
    const int mbase = ch * (NS / CHA);
    constexpr int NTS = (NS / CHA) / 64;          // 8

    auto stage = [&](int bf, int t) {
        const _Float16* ks = kb + (size_t)(mbase + t * 64) * NC;
#pragma unroll
        for (int q = 0; q < 2; ++q)
            GLOAD_LDS(ks + goffk[q], &Kl[bf][(w * 2 + q) * 512]);
    };

    float mrun = NEGBIG, srun = 0.f;
    stage(0, 0);
    for (int t = 0; t < NTS; ++t) {
        const int cur = t & 1;
        const int mg0 = mbase + t * 64;
        if (t + 1 < NTS) { stage(cur ^ 1, t + 1); WAITV(2); }
        else             { WAITV(0); }
        SBAR(); SCHED0();
#pragma unroll
        for (int half = 0; half < 2; ++half) {
            const int m0 = half * 32;
            f32x4 a0 = {0.f, 0.f, 0.f, 0.f}, a1 = {0.f, 0.f, 0.f, 0.f};
#pragma unroll
            for (int j = 0; j < 4; ++j) {
                f16x8 k0 = *(const f16x8*)&Kl[cur][(m0 + ln) * 128 + ((((j << 2) + g) ^ swz) << 3)];
                f16x8 k1 = *(const f16x8*)&Kl[cur][(m0 + 16 + ln) * 128 + ((((j << 2) + g) ^ swz) << 3)];
                a0 = MFMA16(k0, qf[j], a0);
                a1 = MFMA16(k1, qf[j], a1);
            }
            float vv[8];
#pragma unroll
            for (int r = 0; r < 4; ++r) {
                int mi = mg0 + m0 + 4 * g + r;
                vv[r]     = (mi      < lenr) ? a0[r] * F_INV_TEMP : NEGBIG;
                vv[4 + r] = (mi + 16 < lenr) ? a1[r] * F_INV_TEMP : NEGBIG;
            }
            float cmax = fmaxf(fmaxf(fmaxf(vv[0], vv[1]), fmaxf(vv[2], vv[3])),
                               fmaxf(fmaxf(vv[4], vv[5]), fmaxf(vv[6], vv[7])));
            float newm = fmaxf(mrun, cmax);
            float ssum = 0.f;
#pragma unroll
            for (int i = 0; i < 8; ++i) ssum += __expf(vv[i] - newm);
            srun = srun * __expf(mrun - newm) + ssum;
            mrun = newm;
        }
        SBAR();
    }
#pragma unroll
    for (int off = 16; off <= 32; off <<= 1) {
        float om = __shfl_xor(mrun, off, 64);
        float os = __shfl_xor(srun, off, 64);
        float nm = fmaxf(mrun, om);
        srun = srun * __expf(mrun - nm) + os * __expf(om - nm);
        mrun = nm;
    }
    if (g == 0) {
        size_t row = (size_t)b * NS + n_base + ln;
        pM[row * CHA + ch] = mrun;
        pS[row * CHA + ch] = srun;
    }
}

// ---------------- K4: combine partials + zero-init out0 (replaces memset) ----------------
__global__ void k_combine(const float* __restrict__ pM, const float* __restrict__ pS,
                          const int* __restrict__ lens,
                          float* __restrict__ rM, float* __restrict__ rI,
                          float* __restrict__ out0) {
    int row = blockIdx.x * 256 + threadIdx.x;
    int b = row >> 11, n = row & (NS - 1);
    float M = NEGBIG;
#pragma unroll
    for (int c = 0; c < CHA; ++c) M = fmaxf(M, pM[(size_t)row * CHA + c]);
    float S = 0.f;
#pragma unroll
    for (int c = 0; c < CHA; ++c) {
        float pm = pM[(size_t)row * CHA + c];
        if (pm > -1e29f) S += pS[(size_t)row * CHA + c] * __expf(pm - M);
    }
    rM[row] = M;
    rI[row] = (n < lens[b]) ? 1.f / S : 0.f;

    // zero out0: 4.2M floats over 128 blocks x 256 threads, coalesced float4
    float4 z = make_float4(0.f, 0.f, 0.f, 0.f);
    float* o = out0 + (size_t)blockIdx.x * 32768;
#pragma unroll
    for (int i = 0; i < 32; ++i)
        *(float4*)(o + i * 1024 + threadIdx.x * 4) = z;
}

// ---------------- K5: pass B — occupancy experiment ----------------
// K is NOT LDS-staged: all 8 waves read the same 16KB K tile through L1 (coalesced
// 16rows x 64B per instruction, L1-resident after first wave). LDS = V(16K)+P(10K)
// = 26.6 KB -> 4+ blocks/CU; __launch_bounds__(512,8) permits 32 waves/CU.
// Per-tile interleaved att stores (r7-r9 lesson: never batch; trickle write-combines).
__global__ __launch_bounds__(512, 8) void k_attn2(const _Float16* __restrict__ qt,
                                                  const _Float16* __restrict__ kt,
                                                  const _Float16* __restrict__ vt,
                                                  const int* __restrict__ lens,
                                                  const float* __restrict__ rM,
                                                  const float* __restrict__ rI,
                                                  float* __restrict__ att,
                                                  float* __restrict__ out0) {
    __shared__ _Float16 Vlds[128 * 64];
    __shared__ _Float16 Plds[8][16][40];
    const int nt = blockIdx.x, ch = blockIdx.y, b = blockIdx.z;
    const int tid = threadIdx.x;
    const int w = tid >> 6, lane = tid & 63, ln = lane & 15, g = lane >> 4;
    const int n_base = nt * 128 + w * 16;
    const int lenr = lens[16 + b];
    const int swz = ln & 7;

    const _Float16* qrow = qt + ((size_t)b * NS + n_base + ln) * NC + g * 8;
    f16x8 qf[4];
#pragma unroll
    for (int j = 0; j < 4; ++j) qf[j] = *(const f16x8*)(qrow + 32 * j);

    const _Float16* kb = kt + (size_t)b * NS * NC;   // [m][c]
    const _Float16* vb = vt + (size_t)b * NC * NS;   // [c][m]

    const size_t row = (size_t)b * NS + n_base + ln;
    const float M = rM[row];
    const float rinv = rI[row];

    f32x4 opv[8];
#pragma unroll
    for (int ct = 0; ct < 8; ++ct) opv[ct] = f32x4{0.f, 0.f, 0.f, 0.f};

    float* attb = att + row * NS;

    f16x8 vreg[2];
    auto load_v = [&](int mg0) {
#pragma unroll
        for (int q = 0; q < 2; ++q) {
            int idx = q * 512 + tid;
            vreg[q] = *(const f16x8*)(vb + (size_t)(idx >> 3) * NS + mg0 + (idx & 7) * 8);
        }
    };
    auto store_v = [&]() {
#pragma unroll
        for (int q = 0; q < 2; ++q) {
            int idx = q * 512 + tid;
            int rv = idx >> 3, sv = idx & 7;
            *(f16x8*)(Vlds + rv * 64 + ((sv ^ (rv & 7)) << 3)) = vreg[q];
        }
    };

    constexpr int NT = (NS / CHB) / 64;           // 16
    load_v(ch * (NS / CHB));
    for (int it = 0; it < NT; ++it) {
        const int mg0 = ch * (NS / CHB) + it * 64;
        const bool live = (mg0 < lenr);              // block-uniform
        __syncthreads();
        if (live) store_v();
        if (it + 1 < NT) load_v(mg0 + 64);
        __syncthreads();
        if (!live) {
            f32x4 z = {0.f, 0.f, 0.f, 0.f};
#pragma unroll
            for (int h = 0; h < 4; ++h)
                *(f32x4*)(attb + mg0 + h * 16 + 4 * g) = z;
            continue;
        }
        const _Float16* kt0 = kb + (size_t)(mg0 + ln) * NC + g * 8;
#pragma unroll
        for (int half = 0; half < 2; ++half) {
            const int m0 = half * 32;
            const _Float16* kr0 = kt0 + (size_t)m0 * NC;
            const _Float16* kr1 = kr0 + 16 * NC;
            f32x4 a0 = {0.f, 0.f, 0.f, 0.f}, a1 = {0.f, 0.f, 0.f, 0.f};
            a0 = MFMA16(*(const f16x8*)(kr0 +  0), qf[0], a0);
            a0 = MFMA16(*(const f16x8*)(kr0 + 32), qf[1], a0);
            a0 = MFMA16(*(const f16x8*)(kr0 + 64), qf[2], a0);
            a0 = MFMA16(*(const f16x8*)(kr0 + 96), qf[3], a0);
            a1 = MFMA16(*(const f16x8*)(kr1 +  0), qf[0], a1);
            a1 = MFMA16(*(const f16x8*)(kr1 + 32), qf[1], a1);
            a1 = MFMA16(*(const f16x8*)(kr1 + 64), qf[2], a1);
            a1 = MFMA16(*(const f16x8*)(kr1 + 96), qf[3], a1);

            f32x4 p0, p1;
#pragma unroll
            for (int r = 0; r < 4; ++r) {
                int mi = mg0 + m0 + 4 * g + r;
                float v0 = (mi      < lenr) ? a0[r] * F_INV_TEMP : NEGBIG;
                float v1 = (mi + 16 < lenr) ? a1[r] * F_INV_TEMP : NEGBIG;
                p0[r] = __expf(v0 - M) * rinv;
                p1[r] = __expf(v1 - M) * rinv;
            }
            *(f32x4*)(attb + mg0 + m0 + 4 * g)      = p0;
            *(f32x4*)(attb + mg0 + m0 + 16 + 4 * g) = p1;

            f16x4 pk0, pk1;
#pragma unroll
            for (int r = 0; r < 4; ++r) {
                pk0[r] = (_Float16)p0[r];
                pk1[r] = (_Float16)p1[r];
            }
            *(f16x4*)&Plds[w][ln][4 * g]      = pk0;
            *(f16x4*)&Plds[w][ln][16 + 4 * g] = pk1;
            f16x8 pf = *(const f16x8*)&Plds[w][ln][g * 8];

#pragma unroll
            for (int ct = 0; ct < 8; ++ct) {
                f16x8 vf = *(const f16x8*)(Vlds + (ct * 16 + ln) * 64 +
                                           (((half * 4 + g) ^ swz) << 3));
                opv[ct] = MFMA16(pf, vf, opv[ct]);
            }
        }
    }

    // partial PV -> out0 (exactly CHB=2 adds per element: commutative, deterministic)
    float* ob = out0 + (size_t)b * NC * NS;
#pragma unroll
    for (int ct = 0; ct < 8; ++ct) {
        float* dst = ob + (size_t)(ct * 16 + ln) * NS + n_base + 4 * g;
#pragma unroll
        for (int r = 0; r < 4; ++r) unsafeAtomicAdd(dst + r, opv[ct][r]);
    }
}

// ---------------- launch ----------------
extern "C" void kernel_launch(void* const* d_in, const int* in_sizes, int n_in,
                              void* d_out, int out_size, void* d_ws, size_t ws_size,
                              hipStream_t stream) {
    const float* xt   = (const float*)d_in[0];
    const float* xr   = (const float*)d_in[1];
    const int*   lmt  = (const int*)d_in[2];
    const int*   lmr  = (const int*)d_in[3];
    const float* xrgb = (const float*)d_in[6];
    const float* Wq   = (const float*)d_in[9];
    const float* bq   = (const float*)d_in[10];
    const float* Wk   = (const float*)d_in[11];
    const float* bk   = (const float*)d_in[12];
    const float* Wv   = (const float*)d_in[13];
    const float* bv   = (const float*)d_in[14];

    float* out0 = (float*)d_out;                       // [NB][NC][NS]
    float* att  = out0 + (size_t)NB * NC * NS;         // [NB][NS][NS]

    float* ws   = (float*)d_ws;
    int*   lens = (int*)d_ws;
    _Float16* h = (_Float16*)(ws + F16_OFF);
    _Float16* qt  = h + QT_H;
    _Float16* kt  = h + KT_H;
    _Float16* vt  = h + VT_H;
    _Float16* W16 = h + W16_H;

    k_lens<<<32, 256, 0, stream>>>(lmt, lmr, lens);
    k_prep<<<NC * NC / 256, 256, 0, stream>>>(Wq, Wk, Wv, W16);

    dim3 gproj(NS / 64, NB);
    k_qkv<true,  0><<<gproj, 256, 0, stream>>>(xt,   W16,               bq, qt, nullptr);
    k_qkv<true,  1><<<gproj, 256, 0, stream>>>(xr,   W16 + NC * NC,     bk, kt, nullptr);
    k_qkv<false, 2><<<gproj, 256, 0, stream>>>(xrgb, W16 + 2 * NC * NC, bv, nullptr, vt);

    dim3 gstats(NS / 128, CHA, NB);
    k_stats<<<gstats, 512, 0, stream>>>(qt, kt, lens, ws + PM_OFF, ws + PS_OFF);
    k_combine<<<(NB * NS) / 256, 256, 0, stream>>>(ws + PM_OFF, ws + PS_OFF, lens,
                                                   ws + RM_OFF, ws + RI_OFF, out0);

    dim3 gattn(NS / 128, CHB, NB);
    k_attn2<<<gattn, 512, 0, stream>>>(qt, kt, vt, lens,
                                       ws + RM_OFF, ws + RI_OFF, att, out0);
}

// Round 12
// 285.685 us; speedup vs baseline: 2.0039x; 2.0039x over previous
//
#include <hip/hip_runtime.h>
#include <math.h>

constexpr int NB = 16;
constexpr int NC = 128;
constexpr int NS = 2048;          // Np1 == Mp1 == S
constexpr float F_INV_TEMP = 100.0f;
constexpr float F_EPS = 1e-5f;
constexpr float NEGBIG = -1e30f;
constexpr int CHA = 4;            // stats m-chunks (512 each)
constexpr int CHB = 2;            // pass-B m-chunks (1024 each; ==2 keeps atomic merge deterministic)

typedef __attribute__((ext_vector_type(8))) _Float16 f16x8;
typedef __attribute__((ext_vector_type(4))) _Float16 f16x4;
typedef __attribute__((ext_vector_type(4))) float f32x4;

#define MFMA16(a, b, c) __builtin_amdgcn_mfma_f32_16x16x32_f16((a), (b), (c), 0, 0, 0)
#define GLOAD_LDS(g, l) __builtin_amdgcn_global_load_lds(                      \
    (const __attribute__((address_space(1))) void*)(g),                       \
    (__attribute__((address_space(3))) void*)(l), 16, 0, 0)
#define SBAR()   __builtin_amdgcn_s_barrier()
#define WAITV(N) asm volatile("s_waitcnt vmcnt(" #N ")" ::: "memory")
#define SCHED0() __builtin_amdgcn_sched_barrier(0)

// ---- workspace layout (float offsets) ----
constexpr size_t RM_OFF = 64;                        // rowmax [NB*NS]
constexpr size_t RI_OFF = RM_OFF + (size_t)NB * NS;  // rowinv [NB*NS]
constexpr size_t PM_OFF = RI_OFF + (size_t)NB * NS;  // partial max [NB*NS][CHA]
constexpr size_t PS_OFF = PM_OFF + (size_t)NB * NS * CHA;
constexpr size_t F16_OFF = PS_OFF + (size_t)NB * NS * CHA;
// fp16 region (element offsets):
constexpr size_t QT_H   = 0;                                  // q [b][s][c]
constexpr size_t KT_H   = QT_H + (size_t)NB * NS * NC;        // k [b][s][c]
constexpr size_t VT_H   = KT_H + (size_t)NB * NS * NC;        // v [b][c][s]
constexpr size_t W16_H  = VT_H + (size_t)NB * NS * NC;        // W16 [3][128][128]

// ---------------- K0: ragged lengths ----------------
__global__ void k_lens(const int* __restrict__ lm_t, const int* __restrict__ lm_r,
                       int* __restrict__ lens) {
    int b = blockIdx.x & 15;
    const int* src = (blockIdx.x < 16) ? lm_t : lm_r;
    src += b * 4096;
    int m = 0;
    for (int i = threadIdx.x; i < 4096; i += 256) m = max(m, src[i]);
    for (int off = 32; off; off >>= 1) m = max(m, __shfl_down(m, off, 64));
    __shared__ int red[4];
    if ((threadIdx.x & 63) == 0) red[threadIdx.x >> 6] = m;
    __syncthreads();
    if (threadIdx.x == 0) {
        m = max(max(red[0], red[1]), max(red[2], red[3]));
        lens[blockIdx.x] = m + 1;   // [0..15]=len_t, [16..31]=len_r
    }
}

// ---------------- K0b: convert W to fp16 ----------------
__global__ void k_prep(const float* __restrict__ Wq, const float* __restrict__ Wk,
                       const float* __restrict__ Wv, _Float16* __restrict__ W16) {
    int i = blockIdx.x * 256 + threadIdx.x;
    W16[i]               = (_Float16)Wq[i];
    W16[i + NC * NC]     = (_Float16)Wk[i];
    W16[i + 2 * NC * NC] = (_Float16)Wv[i];
}

// ---------------- K1: fused center-norm + projection GEMM (MFMA) ----------------
// MODE 0/1: out [b][s][c] fp16 (q,k); MODE 2: vout [b][c][s] fp16 (v)
template <bool NORM, int MODE>
__global__ __launch_bounds__(256) void k_qkv(const float* __restrict__ x,
                                             const _Float16* __restrict__ W16,
                                             const float* __restrict__ bias,
                                             _Float16* __restrict__ out,
                                             _Float16* __restrict__ vout) {
    __shared__ __align__(16) char smem[48 * 1024];
    float*    xs = (float*)smem;                        // [128][64] fp32 (32 KB)
    _Float16* xn = (_Float16*)(smem + 32 * 1024);       // [64][16 slots of 8] swizzled (16 KB)
    _Float16 (*Vt)[72] = (_Float16 (*)[72])smem;        // MODE2: [128][72] aliases xs
    __shared__ float ps[4][64], pq[4][64], cmean[64], cscale[64];

    const int b  = blockIdx.y;
    const int s0 = blockIdx.x * 64;
    const float* xb = x + (size_t)b * NC * NS + s0;

    for (int idx = threadIdx.x; idx < NC * 16; idx += 256) {
        int c = idx >> 4, j = (idx & 15) << 2;
        *(float4*)&xs[c * 64 + j] = *(const float4*)&xb[(size_t)c * NS + j];
    }
    __syncthreads();

    if (NORM) {
        int j = threadIdx.x & 63, p = threadIdx.x >> 6;
        float sum = 0.f, ssq = 0.f;
#pragma unroll
        for (int cc = 0; cc < 32; ++cc) {
            float v = xs[(p * 32 + cc) * 64 + j];
            sum += v; ssq += v * v;
        }
        ps[p][j] = sum; pq[p][j] = ssq;
        __syncthreads();
        if (threadIdx.x < 64) {
            float sm = ps[0][j] + ps[1][j] + ps[2][j] + ps[3][j];
            float sq = pq[0][j] + pq[1][j] + pq[2][j] + pq[3][j];
            float mean = sm * (1.f / NC);
            float var = sq - (float)NC * mean * mean;
            cmean[j]  = mean;
            cscale[j] = 1.f / (sqrtf(fmaxf(var, 0.f)) + F_EPS);
        }
        __syncthreads();
    }

    {
        const int lane = threadIdx.x & 63;           // s
        const int w4   = threadIdx.x >> 6;           // c chunk of 32
        const float mn = NORM ? cmean[lane] : 0.f;
        const float sc = NORM ? cscale[lane] : 1.f;
#pragma unroll
        for (int q = 0; q < 4; ++q) {
            f16x8 v8;
#pragma unroll
            for (int i = 0; i < 8; ++i)
                v8[i] = (_Float16)((xs[(w4 * 32 + q * 8 + i) * 64 + lane] - mn) * sc);
            *(f16x8*)(xn + lane * 128 + (((w4 * 4 + q) ^ (lane & 7)) << 3)) = v8;
        }
    }
    __syncthreads();   // xn ready; xs dead (Vt may alias it)

    const int w = threadIdx.x >> 6, lane = threadIdx.x & 63;
    const int ln = lane & 15, g = lane >> 4;
    const int sl = w * 16 + ln;                      // local s row (0..63)

    f16x8 xf[4];
#pragma unroll
    for (int jj = 0; jj < 4; ++jj)
        xf[jj] = *(const f16x8*)(xn + sl * 128 + (((jj * 4 + g) ^ (ln & 7)) << 3));

#pragma unroll
    for (int ot = 0; ot < 8; ++ot) {
        const _Float16* wrow = W16 + (size_t)(ot * 16 + ln) * NC + g * 8;
        f32x4 acc = {0.f, 0.f, 0.f, 0.f};
        acc = MFMA16(*(const f16x8*)(wrow),      xf[0], acc);
        acc = MFMA16(*(const f16x8*)(wrow + 32), xf[1], acc);
        acc = MFMA16(*(const f16x8*)(wrow + 64), xf[2], acc);
        acc = MFMA16(*(const f16x8*)(wrow + 96), xf[3], acc);
        const float4 bv = *(const float4*)&bias[ot * 16 + 4 * g];
        f16x4 res;
        res[0] = (_Float16)(acc[0] + bv.x);
        res[1] = (_Float16)(acc[1] + bv.y);
        res[2] = (_Float16)(acc[2] + bv.z);
        res[3] = (_Float16)(acc[3] + bv.w);
        if (MODE < 2) {
            *(f16x4*)(out + ((size_t)b * NS + s0 + sl) * NC + ot * 16 + 4 * g) = res;
        } else {
#pragma unroll
            for (int r = 0; r < 4; ++r)
                Vt[ot * 16 + 4 * g + r][sl] = res[r];
        }
    }
    if (MODE == 2) {
        __syncthreads();
        int o = threadIdx.x >> 1, sh = threadIdx.x & 1;
        _Float16* vr = vout + ((size_t)b * NC + o) * NS + s0 + sh * 32;
        const _Float16* src = &Vt[o][sh * 32];
#pragma unroll
        for (int i = 0; i < 4; ++i) *(f16x8*)(vr + i * 8) = *(const f16x8*)(src + i * 8);
    }
}

// ---------------- K3: partial softmax stats (split-m, async pipeline) ----------------
// r10 version verbatim (proven): natural 3-D grid, gload_lds dbuf, counted vmcnt.
__global__ __launch_bounds__(512, 6) void k_stats(const _Float16* __restrict__ qt,
                                                  const _Float16* __restrict__ kt,
                                                  const int* __restrict__ lens,
                                                  float* __restrict__ pM,
                                                  float* __restrict__ pS) {
    __shared__ __align__(16) _Float16 Kl[2][64 * 128];
    const int nt = blockIdx.x, ch = blockIdx.y, b = blockIdx.z;
    const int tid = threadIdx.x;
    const int w = tid >> 6, lane = tid & 63, ln = lane & 15, g = lane >> 4;
    const int n_base = nt * 128 + w * 16;
    const int lenr = lens[16 + b];
    const int swz = ln & 7;

    const _Float16* qrow = qt + ((size_t)b * NS + n_base + ln) * NC + g * 8;
    f16x8 qf[4];
#pragma unroll
    for (int j = 0; j < 4; ++j) qf[j] = *(const f16x8*)(qrow + 32 * j);

    const _Float16* kb = kt + (size_t)b * NS * NC;

    size_t goffk[2];
#pragma unroll
    for (int q = 0; q < 2; ++q) {
        const int ck = w * 2 + q;
        const int r  = ck * 4 + (lane >> 4);
        const int j  = lane & 15;
        goffk[q] = (size_t)r * NC + ((j ^ (r & 7)) << 3);
    }
    const int mbase = ch * (NS / CHA);
    constexpr int NTS = (NS / CHA) / 64;          // 8

    auto stage = [&](int bf, int t) {
        const _Float16* ks = kb + (size_t)(mbase + t * 64) * NC;
#pragma unroll
        for (int q = 0; q < 2; ++q)
            GLOAD_LDS(ks + goffk[q], &Kl[bf][(w * 2 + q) * 512]);
    };

    float mrun = NEGBIG, srun = 0.f;
    stage(0, 0);
    for (int t = 0; t < NTS; ++t) {
        const int cur = t & 1;
        const int mg0 = mbase + t * 64;
        if (t + 1 < NTS) { stage(cur ^ 1, t + 1); WAITV(2); }
        else             { WAITV(0); }
        SBAR(); SCHED0();
#pragma unroll
        for (int half = 0; half < 2; ++half) {
            const int m0 = half * 32;
            f32x4 a0 = {0.f, 0.f, 0.f, 0.f}, a1 = {0.f, 0.f, 0.f, 0.f};
#pragma unroll
            for (int j = 0; j < 4; ++j) {
                f16x8 k0 = *(const f16x8*)&Kl[cur][(m0 + ln) * 128 + ((((j << 2) + g) ^ swz) << 3)];
                f16x8 k1 = *(const f16x8*)&Kl[cur][(m0 + 16 + ln) * 128 + ((((j << 2) + g) ^ swz) << 3)];
                a0 = MFMA16(k0, qf[j], a0);
                a1 = MFMA16(k1, qf[j], a1);
            }
            float vv[8];
#pragma unroll
            for (int r = 0; r < 4; ++r) {
                int mi = mg0 + m0 + 4 * g + r;
                vv[r]     = (mi      < lenr) ? a0[r] * F_INV_TEMP : NEGBIG;
                vv[4 + r] = (mi + 16 < lenr) ? a1[r] * F_INV_TEMP : NEGBIG;
            }
            float cmax = fmaxf(fmaxf(fmaxf(vv[0], vv[1]), fmaxf(vv[2], vv[3])),
                               fmaxf(fmaxf(vv[4], vv[5]), fmaxf(vv[6], vv[7])));
            float newm = fmaxf(mrun, cmax);
            float ssum = 0.f;
#pragma unroll
            for (int i = 0; i < 8; ++i) ssum += __expf(vv[i] - newm);
            srun = srun * __expf(mrun - newm) + ssum;
            mrun = newm;
        }
        SBAR();
    }
#pragma unroll
    for (int off = 16; off <= 32; off <<= 1) {
        float om = __shfl_xor(mrun, off, 64);
        float os = __shfl_xor(srun, off, 64);
        float nm = fmaxf(mrun, om);
        srun = srun * __expf(mrun - nm) + os * __expf(om - nm);
        mrun = nm;
    }
    if (g == 0) {
        size_t row = (size_t)b * NS + n_base + ln;
        pM[row * CHA + ch] = mrun;
        pS[row * CHA + ch] = srun;
    }
}

// ---------------- K4: combine partials + zero-init out0 (replaces memset) ----------------
__global__ void k_combine(const float* __restrict__ pM, const float* __restrict__ pS,
                          const int* __restrict__ lens,
                          float* __restrict__ rM, float* __restrict__ rI,
                          float* __restrict__ out0) {
    int row = blockIdx.x * 256 + threadIdx.x;
    int b = row >> 11, n = row & (NS - 1);
    float M = NEGBIG;
#pragma unroll
    for (int c = 0; c < CHA; ++c) M = fmaxf(M, pM[(size_t)row * CHA + c]);
    float S = 0.f;
#pragma unroll
    for (int c = 0; c < CHA; ++c) {
        float pm = pM[(size_t)row * CHA + c];
        if (pm > -1e29f) S += pS[(size_t)row * CHA + c] * __expf(pm - M);
    }
    rM[row] = M;
    rI[row] = (n < lens[b]) ? 1.f / S : 0.f;

    // zero out0: 4.2M floats over 128 blocks x 256 threads, coalesced float4
    float4 z = make_float4(0.f, 0.f, 0.f, 0.f);
    float* o = out0 + (size_t)blockIdx.x * 32768;
#pragma unroll
    for (int i = 0; i < 32; ++i)
        *(float4*)(o + i * 1024 + threadIdx.x * 4) = z;
}

// ---------------- K5: pass B — 256-thread blocks for 4 blocks/CU residency ----------
// r11 lesson: K LDS staging is mandatory (removing it -> L1 thrash, FETCH x10) but
// the memory system sustained 4.1 TB/s there -> r10's 2.74 TB/s was MLP-limited
// (grid 512 = 2 blocks/CU). This version: 4 waves/block, 64 n-rows, nt=32 ->
// grid 1024 = 4 blocks/CU (LDS 37 KB). Same verified math, trickled att stores
// (r7-r9 lesson: never batch stores), reg-dbuf K/V staging.
__global__ __launch_bounds__(256, 4) void k_attn2(const _Float16* __restrict__ qt,
                                                  const _Float16* __restrict__ kt,
                                                  const _Float16* __restrict__ vt,
                                                  const int* __restrict__ lens,
                                                  const float* __restrict__ rM,
                                                  const float* __restrict__ rI,
                                                  float* __restrict__ att,
                                                  float* __restrict__ out0) {
    __shared__ _Float16 Klds[64 * 128];
    __shared__ _Float16 Vlds[128 * 64];
    __shared__ _Float16 Plds[4][16][40];
    const int nt = blockIdx.x, ch = blockIdx.y, b = blockIdx.z;
    const int tid = threadIdx.x;
    const int w = tid >> 6, lane = tid & 63, ln = lane & 15, g = lane >> 4;
    const int n_base = nt * 64 + w * 16;
    const int lenr = lens[16 + b];
    const int swz = ln & 7;

    const _Float16* qrow = qt + ((size_t)b * NS + n_base + ln) * NC + g * 8;
    f16x8 qf[4];
#pragma unroll
    for (int j = 0; j < 4; ++j) qf[j] = *(const f16x8*)(qrow + 32 * j);

    const _Float16* kb = kt + (size_t)b * NS * NC;   // [m][c]
    const _Float16* vb = vt + (size_t)b * NC * NS;   // [c][m]

    const size_t row = (size_t)b * NS + n_base + ln;
    const float M = rM[row];
    const float rinv = rI[row];

    f32x4 opv[8];
#pragma unroll
    for (int ct = 0; ct < 8; ++ct) opv[ct] = f32x4{0.f, 0.f, 0.f, 0.f};

    float* attb = att + row * NS;

    f16x8 kreg[4], vreg[4];
    auto load_kv = [&](int mg0) {
#pragma unroll
        for (int q = 0; q < 4; ++q) {
            int idx = q * 256 + tid;
            kreg[q] = *(const f16x8*)(kb + (size_t)(mg0 + (idx >> 4)) * NC + (idx & 15) * 8);
            vreg[q] = *(const f16x8*)(vb + (size_t)(idx >> 3) * NS + mg0 + (idx & 7) * 8);
        }
    };
    auto store_kv = [&]() {
#pragma unroll
        for (int q = 0; q < 4; ++q) {
            int idx = q * 256 + tid;
            int r = idx >> 4, s = idx & 15;
            *(f16x8*)(Klds + r * 128 + ((s ^ (r & 7)) << 3)) = kreg[q];
            int rv = idx >> 3, sv = idx & 7;
            *(f16x8*)(Vlds + rv * 64 + ((sv ^ (rv & 7)) << 3)) = vreg[q];
        }
    };

    constexpr int NT = (NS / CHB) / 64;           // 16
    load_kv(ch * (NS / CHB));
    for (int it = 0; it < NT; ++it) {
        const int mg0 = ch * (NS / CHB) + it * 64;
        const bool live = (mg0 < lenr);              // block-uniform
        __syncthreads();
        if (live) store_kv();
        if (it + 1 < NT) load_kv(mg0 + 64);
        __syncthreads();
        if (!live) {
            f32x4 z = {0.f, 0.f, 0.f, 0.f};
#pragma unroll
            for (int h = 0; h < 4; ++h)
                *(f32x4*)(attb + mg0 + h * 16 + 4 * g) = z;
            continue;
        }
#pragma unroll
        for (int half = 0; half < 2; ++half) {
            const int m0 = half * 32;
            f32x4 a0 = {0.f, 0.f, 0.f, 0.f}, a1 = {0.f, 0.f, 0.f, 0.f};
#pragma unroll
            for (int j = 0; j < 4; ++j) {
                f16x8 k0 = *(const f16x8*)(Klds + (m0 + ln) * 128 + ((((j << 2) + g) ^ swz) << 3));
                f16x8 k1 = *(const f16x8*)(Klds + (m0 + 16 + ln) * 128 + ((((j << 2) + g) ^ swz) << 3));
                a0 = MFMA16(k0, qf[j], a0);
                a1 = MFMA16(k1, qf[j], a1);
            }
            f32x4 p0, p1;
#pragma unroll
            for (int r = 0; r < 4; ++r) {
                int mi = mg0 + m0 + 4 * g + r;
                float v0 = (mi      < lenr) ? a0[r] * F_INV_TEMP : NEGBIG;
                float v1 = (mi + 16 < lenr) ? a1[r] * F_INV_TEMP : NEGBIG;
                p0[r] = __expf(v0 - M) * rinv;
                p1[r] = __expf(v1 - M) * rinv;
            }
            *(f32x4*)(attb + mg0 + m0 + 4 * g)      = p0;
            *(f32x4*)(attb + mg0 + m0 + 16 + 4 * g) = p1;

            f16x4 pk0, pk1;
#pragma unroll
            for (int r = 0; r < 4; ++r) {
                pk0[r] = (_Float16)p0[r];
                pk1[r] = (_Float16)p1[r];
            }
            *(f16x4*)&Plds[w][ln][4 * g]      = pk0;
            *(f16x4*)&Plds[w][ln][16 + 4 * g] = pk1;
            f16x8 pf = *(const f16x8*)&Plds[w][ln][g * 8];

#pragma unroll
            for (int ct = 0; ct < 8; ++ct) {
                f16x8 vf = *(const f16x8*)(Vlds + (ct * 16 + ln) * 64 +
                                           (((half * 4 + g) ^ swz) << 3));
                opv[ct] = MFMA16(pf, vf, opv[ct]);
            }
        }
    }

    // partial PV -> out0 (exactly CHB=2 adds per element: commutative, deterministic)
    float* ob = out0 + (size_t)b * NC * NS;
#pragma unroll
    for (int ct = 0; ct < 8; ++ct) {
        float* dst = ob + (size_t)(ct * 16 + ln) * NS + n_base + 4 * g;
#pragma unroll
        for (int r = 0; r < 4; ++r) unsafeAtomicAdd(dst + r, opv[ct][r]);
    }
}

// ---------------- launch ----------------
extern "C" void kernel_launch(void* const* d_in, const int* in_sizes, int n_in,
                              void* d_out, int out_size, void* d_ws, size_t ws_size,
                              hipStream_t stream) {
    const float* xt   = (const float*)d_in[0];
    const float* xr   = (const float*)d_in[1];
    const int*   lmt  = (const int*)d_in[2];
    const int*   lmr  = (const int*)d_in[3];
    const float* xrgb = (const float*)d_in[6];
    const float* Wq   = (const float*)d_in[9];
    const float* bq   = (const float*)d_in[10];
    const float* Wk   = (const float*)d_in[11];
    const float* bk   = (const float*)d_in[12];
    const float* Wv   = (const float*)d_in[13];
    const float* bv   = (const float*)d_in[14];

    float* out0 = (float*)d_out;                       // [NB][NC][NS]
    float* att  = out0 + (size_t)NB * NC * NS;         // [NB][NS][NS]

    float* ws   = (float*)d_ws;
    int*   lens = (int*)d_ws;
    _Float16* h = (_Float16*)(ws + F16_OFF);
    _Float16* qt  = h + QT_H;
    _Float16* kt  = h + KT_H;
    _Float16* vt  = h + VT_H;
    _Float16* W16 = h + W16_H;

    k_lens<<<32, 256, 0, stream>>>(lmt, lmr, lens);
    k_prep<<<NC * NC / 256, 256, 0, stream>>>(Wq, Wk, Wv, W16);

    dim3 gproj(NS / 64, NB);
    k_qkv<true,  0><<<gproj, 256, 0, stream>>>(xt,   W16,               bq, qt, nullptr);
    k_qkv<true,  1><<<gproj, 256, 0, stream>>>(xr,   W16 + NC * NC,     bk, kt, nullptr);
    k_qkv<false, 2><<<gproj, 256, 0, stream>>>(xrgb, W16 + 2 * NC * NC, bv, nullptr, vt);

    dim3 gstats(NS / 128, CHA, NB);
    k_stats<<<gstats, 512, 0, stream>>>(qt, kt, lens, ws + PM_OFF, ws + PS_OFF);
    k_combine<<<(NB * NS) / 256, 256, 0, stream>>>(ws + PM_OFF, ws + PS_OFF, lens,
                                                   ws + RM_OFF, ws + RI_OFF, out0);

    dim3 gattn(NS / 64, CHB, NB);
    k_attn2<<<gattn, 256, 0, stream>>>(qt, kt, vt, lens,
                                       ws + RM_OFF, ws + RI_OFF, att, out0);
}

// Round 13
// 165.291 us; speedup vs baseline: 3.4635x; 1.7284x over previous
//
#include <hip/hip_runtime.h>
#include <math.h>

constexpr int NB = 16;
constexpr int NC = 128;
constexpr int NS = 2048;          // Np1 == Mp1 == S
constexpr float F_INV_TEMP = 100.0f;
constexpr float F_EPS = 1e-5f;
constexpr float NEGBIG = -1e30f;
constexpr int CHA = 4;            // stats m-chunks (512 each)

typedef __attribute__((ext_vector_type(8))) _Float16 f16x8;
typedef __attribute__((ext_vector_type(4))) _Float16 f16x4;
typedef __attribute__((ext_vector_type(4))) float f32x4;

#define MFMA16(a, b, c) __builtin_amdgcn_mfma_f32_16x16x32_f16((a), (b), (c), 0, 0, 0)
#define GLOAD_LDS(g, l) __builtin_amdgcn_global_load_lds(                      \
    (const __attribute__((address_space(1))) void*)(g),                       \
    (__attribute__((address_space(3))) void*)(l), 16, 0, 0)
#define SBAR()   __builtin_amdgcn_s_barrier()
#define WAITV(N) asm volatile("s_waitcnt vmcnt(" #N ")" ::: "memory")
#define SCHED0() __builtin_amdgcn_sched_barrier(0)

// ---- workspace layout (float offsets) ----
constexpr size_t RM_OFF = 64;                        // rowmax [NB*NS]
constexpr size_t RI_OFF = RM_OFF + (size_t)NB * NS;  // rowinv [NB*NS]
constexpr size_t PM_OFF = RI_OFF + (size_t)NB * NS;  // partial max [NB*NS][CHA]
constexpr size_t PS_OFF = PM_OFF + (size_t)NB * NS * CHA;
constexpr size_t F16_OFF = PS_OFF + (size_t)NB * NS * CHA;
// fp16 region (element offsets):
constexpr size_t QT_H   = 0;                                  // q [b][s][c]
constexpr size_t KT_H   = QT_H + (size_t)NB * NS * NC;        // k [b][s][c]
constexpr size_t VT_H   = KT_H + (size_t)NB * NS * NC;        // v [b][c][s]
constexpr size_t W16_H  = VT_H + (size_t)NB * NS * NC;        // W16 [3][128][128]

// ---------------- K0: ragged lengths ----------------
__global__ void k_lens(const int* __restrict__ lm_t, const int* __restrict__ lm_r,
                       int* __restrict__ lens) {
    int b = blockIdx.x & 15;
    const int* src = (blockIdx.x < 16) ? lm_t : lm_r;
    src += b * 4096;
    int m = 0;
    for (int i = threadIdx.x; i < 4096; i += 256) m = max(m, src[i]);
    for (int off = 32; off; off >>= 1) m = max(m, __shfl_down(m, off, 64));
    __shared__ int red[4];
    if ((threadIdx.x & 63) == 0) red[threadIdx.x >> 6] = m;
    __syncthreads();
    if (threadIdx.x == 0) {
        m = max(max(red[0], red[1]), max(red[2], red[3]));
        lens[blockIdx.x] = m + 1;   // [0..15]=len_t, [16..31]=len_r
    }
}

// ---------------- K0b: convert W to fp16 ----------------
__global__ void k_prep(const float* __restrict__ Wq, const float* __restrict__ Wk,
                       const float* __restrict__ Wv, _Float16* __restrict__ W16) {
    int i = blockIdx.x * 256 + threadIdx.x;
    W16[i]               = (_Float16)Wq[i];
    W16[i + NC * NC]     = (_Float16)Wk[i];
    W16[i + 2 * NC * NC] = (_Float16)Wv[i];
}

// ---------------- K1: fused center-norm + projection GEMM (MFMA) ----------------
// MODE 0/1: out [b][s][c] fp16 (q,k); MODE 2: vout [b][c][s] fp16 (v)
template <bool NORM, int MODE>
__global__ __launch_bounds__(256) void k_qkv(const float* __restrict__ x,
                                             const _Float16* __restrict__ W16,
                                             const float* __restrict__ bias,
                                             _Float16* __restrict__ out,
                                             _Float16* __restrict__ vout) {
    __shared__ __align__(16) char smem[48 * 1024];
    float*    xs = (float*)smem;                        // [128][64] fp32 (32 KB)
    _Float16* xn = (_Float16*)(smem + 32 * 1024);       // [64][16 slots of 8] swizzled (16 KB)
    _Float16 (*Vt)[72] = (_Float16 (*)[72])smem;        // MODE2: [128][72] aliases xs
    __shared__ float ps[4][64], pq[4][64], cmean[64], cscale[64];

    const int b  = blockIdx.y;
    const int s0 = blockIdx.x * 64;
    const float* xb = x + (size_t)b * NC * NS + s0;

    for (int idx = threadIdx.x; idx < NC * 16; idx += 256) {
        int c = idx >> 4, j = (idx & 15) << 2;
        *(float4*)&xs[c * 64 + j] = *(const float4*)&xb[(size_t)c * NS + j];
    }
    __syncthreads();

    if (NORM) {
        int j = threadIdx.x & 63, p = threadIdx.x >> 6;
        float sum = 0.f, ssq = 0.f;
#pragma unroll
        for (int cc = 0; cc < 32; ++cc) {
            float v = xs[(p * 32 + cc) * 64 + j];
            sum += v; ssq += v * v;
        }
        ps[p][j] = sum; pq[p][j] = ssq;
        __syncthreads();
        if (threadIdx.x < 64) {
            float sm = ps[0][j] + ps[1][j] + ps[2][j] + ps[3][j];
            float sq = pq[0][j] + pq[1][j] + pq[2][j] + pq[3][j];
            float mean = sm * (1.f / NC);
            float var = sq - (float)NC * mean * mean;
            cmean[j]  = mean;
            cscale[j] = 1.f / (sqrtf(fmaxf(var, 0.f)) + F_EPS);
        }
        __syncthreads();
    }

    {
        const int lane = threadIdx.x & 63;           // s
        const int w4   = threadIdx.x >> 6;           // c chunk of 32
        const float mn = NORM ? cmean[lane] : 0.f;
        const float sc = NORM ? cscale[lane] : 1.f;
#pragma unroll
        for (int q = 0; q < 4; ++q) {
            f16x8 v8;
#pragma unroll
            for (int i = 0; i < 8; ++i)
                v8[i] = (_Float16)((xs[(w4 * 32 + q * 8 + i) * 64 + lane] - mn) * sc);
            *(f16x8*)(xn + lane * 128 + (((w4 * 4 + q) ^ (lane & 7)) << 3)) = v8;
        }
    }
    __syncthreads();   // xn ready; xs dead (Vt may alias it)

    const int w = threadIdx.x >> 6, lane = threadIdx.x & 63;
    const int ln = lane & 15, g = lane >> 4;
    const int sl = w * 16 + ln;                      // local s row (0..63)

    f16x8 xf[4];
#pragma unroll
    for (int jj = 0; jj < 4; ++jj)
        xf[jj] = *(const f16x8*)(xn + sl * 128 + (((jj * 4 + g) ^ (ln & 7)) << 3));

#pragma unroll
    for (int ot = 0; ot < 8; ++ot) {
        const _Float16* wrow = W16 + (size_t)(ot * 16 + ln) * NC + g * 8;
        f32x4 acc = {0.f, 0.f, 0.f, 0.f};
        acc = MFMA16(*(const f16x8*)(wrow),      xf[0], acc);
        acc = MFMA16(*(const f16x8*)(wrow + 32), xf[1], acc);
        acc = MFMA16(*(const f16x8*)(wrow + 64), xf[2], acc);
        acc = MFMA16(*(const f16x8*)(wrow + 96), xf[3], acc);
        const float4 bv = *(const float4*)&bias[ot * 16 + 4 * g];
        f16x4 res;
        res[0] = (_Float16)(acc[0] + bv.x);
        res[1] = (_Float16)(acc[1] + bv.y);
        res[2] = (_Float16)(acc[2] + bv.z);
        res[3] = (_Float16)(acc[3] + bv.w);
        if (MODE < 2) {
            *(f16x4*)(out + ((size_t)b * NS + s0 + sl) * NC + ot * 16 + 4 * g) = res;
        } else {
#pragma unroll
            for (int r = 0; r < 4; ++r)
                Vt[ot * 16 + 4 * g + r][sl] = res[r];
        }
    }
    if (MODE == 2) {
        __syncthreads();
        int o = threadIdx.x >> 1, sh = threadIdx.x & 1;
        _Float16* vr = vout + ((size_t)b * NC + o) * NS + s0 + sh * 32;
        const _Float16* src = &Vt[o][sh * 32];
#pragma unroll
        for (int i = 0; i < 4; ++i) *(f16x8*)(vr + i * 8) = *(const f16x8*)(src + i * 8);
    }
}

// ---------------- K3: partial softmax stats (split-m, async pipeline) ----------------
// r10 version verbatim (proven): natural 3-D grid, gload_lds dbuf, counted vmcnt.
__global__ __launch_bounds__(512, 6) void k_stats(const _Float16* __restrict__ qt,
                                                  const _Float16* __restrict__ kt,
                                                  const int* __restrict__ lens,
                                                  float* __restrict__ pM,
                                                  float* __restrict__ pS) {
    __shared__ __align__(16) _Float16 Kl[2][64 * 128];
    const int nt = blockIdx.x, ch = blockIdx.y, b = blockIdx.z;
    const int tid = threadIdx.x;
    const int w = tid >> 6, lane = tid & 63, ln = lane & 15, g = lane >> 4;
    const int n_base = nt * 128 + w * 16;
    const int lenr = lens[16 + b];
    const int swz = ln & 7;

    const _Float16* qrow = qt + ((size_t)b * NS + n_base + ln) * NC + g * 8;
    f16x8 qf[4];
#pragma unroll
    for (int j = 0; j < 4; ++j) qf[j] = *(const f16x8*)(qrow + 32 * j);

    const _Float16* kb = kt + (size_t)b * NS * NC;

    size_t goffk[2];
#pragma unroll
    for (int q = 0; q < 2; ++q) {
        const int ck = w * 2 + q;
        const int r  = ck * 4 + (lane >> 4);
        const int j  = lane & 15;
        goffk[q] = (size_t)r * NC + ((j ^ (r & 7)) << 3);
    }
    const int mbase = ch * (NS / CHA);
    constexpr int NTS = (NS / CHA) / 64;          // 8

    auto stage = [&](int bf, int t) {
        const _Float16* ks = kb + (size_t)(mbase + t * 64) * NC;
#pragma unroll
        for (int q = 0; q < 2; ++q)
            GLOAD_LDS(ks + goffk[q], &Kl[bf][(w * 2 + q) * 512]);
    };

    float mrun = NEGBIG, srun = 0.f;
    stage(0, 0);
    for (int t = 0; t < NTS; ++t) {
        const int cur = t & 1;
        const int mg0 = mbase + t * 64;
        if (t + 1 < NTS) { stage(cur ^ 1, t + 1); WAITV(2); }
        else             { WAITV(0); }
        SBAR(); SCHED0();
#pragma unroll
        for (int half = 0; half < 2; ++half) {
            const int m0 = half * 32;
            f32x4 a0 = {0.f, 0.f, 0.f, 0.f}, a1 = {0.f, 0.f, 0.f, 0.f};
#pragma unroll
            for (int j = 0; j < 4; ++j) {
                f16x8 k0 = *(const f16x8*)&Kl[cur][(m0 + ln) * 128 + ((((j << 2) + g) ^ swz) << 3)];
                f16x8 k1 = *(const f16x8*)&Kl[cur][(m0 + 16 + ln) * 128 + ((((j << 2) + g) ^ swz) << 3)];
                a0 = MFMA16(k0, qf[j], a0);
                a1 = MFMA16(k1, qf[j], a1);
            }
            float vv[8];
#pragma unroll
            for (int r = 0; r < 4; ++r) {
                int mi = mg0 + m0 + 4 * g + r;
                vv[r]     = (mi      < lenr) ? a0[r] * F_INV_TEMP : NEGBIG;
                vv[4 + r] = (mi + 16 < lenr) ? a1[r] * F_INV_TEMP : NEGBIG;
            }
            float cmax = fmaxf(fmaxf(fmaxf(vv[0], vv[1]), fmaxf(vv[2], vv[3])),
                               fmaxf(fmaxf(vv[4], vv[5]), fmaxf(vv[6], vv[7])));
            float newm = fmaxf(mrun, cmax);
            float ssum = 0.f;
#pragma unroll
            for (int i = 0; i < 8; ++i) ssum += __expf(vv[i] - newm);
            srun = srun * __expf(mrun - newm) + ssum;
            mrun = newm;
        }
        SBAR();
    }
#pragma unroll
    for (int off = 16; off <= 32; off <<= 1) {
        float om = __shfl_xor(mrun, off, 64);
        float os = __shfl_xor(srun, off, 64);
        float nm = fmaxf(mrun, om);
        srun = srun * __expf(mrun - nm) + os * __expf(om - nm);
        mrun = nm;
    }
    if (g == 0) {
        size_t row = (size_t)b * NS + n_base + ln;
        pM[row * CHA + ch] = mrun;
        pS[row * CHA + ch] = srun;
    }
}

// ---------------- K4: combine partials ----------------
__global__ void k_combine(const float* __restrict__ pM, const float* __restrict__ pS,
                          const int* __restrict__ lens,
                          float* __restrict__ rM, float* __restrict__ rI) {
    int row = blockIdx.x * 256 + threadIdx.x;
    int b = row >> 11, n = row & (NS - 1);
    float M = NEGBIG;
#pragma unroll
    for (int c = 0; c < CHA; ++c) M = fmaxf(M, pM[(size_t)row * CHA + c]);
    float S = 0.f;
#pragma unroll
    for (int c = 0; c < CHA; ++c) {
        float pm = pM[(size_t)row * CHA + c];
        if (pm > -1e29f) S += pS[(size_t)row * CHA + c] * __expf(pm - M);
    }
    rM[row] = M;
    rI[row] = (n < lens[b]) ? 1.f / S : 0.f;
}

// ---------------- K5: pass B — full-m per block (CHB=1): no atomics, no memset ----
// r12 lesson: fewer, bigger blocks win (small blocks double K/V refetch). This block
// owns 128 n-rows x ALL m: PV is complete -> plain f32x4 stores to out0 (removes
// ~126MB of atomic RMW traffic + the 16.8MB zero-init fill). Grid 256 = 1 block/CU.
// Same verified math; trickled per-tile att stores (r7-r9: never batch stores);
// reg-dbuf K/V staging (r11: K LDS staging is mandatory).
__global__ __launch_bounds__(512, 4) void k_attn2(const _Float16* __restrict__ qt,
                                                  const _Float16* __restrict__ kt,
                                                  const _Float16* __restrict__ vt,
                                                  const int* __restrict__ lens,
                                                  const float* __restrict__ rM,
                                                  const float* __restrict__ rI,
                                                  float* __restrict__ att,
                                                  float* __restrict__ out0) {
    __shared__ _Float16 Klds[64 * 128];
    __shared__ _Float16 Vlds[128 * 64];
    __shared__ _Float16 Plds[8][16][40];
    const int nt = blockIdx.x, b = blockIdx.y;
    const int tid = threadIdx.x;
    const int w = tid >> 6, lane = tid & 63, ln = lane & 15, g = lane >> 4;
    const int n_base = nt * 128 + w * 16;
    const int lenr = lens[16 + b];
    const int swz = ln & 7;

    const _Float16* qrow = qt + ((size_t)b * NS + n_base + ln) * NC + g * 8;
    f16x8 qf[4];
#pragma unroll
    for (int j = 0; j < 4; ++j) qf[j] = *(const f16x8*)(qrow + 32 * j);

    const _Float16* kb = kt + (size_t)b * NS * NC;   // [m][c]
    const _Float16* vb = vt + (size_t)b * NC * NS;   // [c][m]

    const size_t row = (size_t)b * NS + n_base + ln;
    const float M = rM[row];
    const float rinv = rI[row];

    f32x4 opv[8];
#pragma unroll
    for (int ct = 0; ct < 8; ++ct) opv[ct] = f32x4{0.f, 0.f, 0.f, 0.f};

    float* attb = att + row * NS;

    f16x8 kreg[2], vreg[2];
    auto load_kv = [&](int mg0) {
#pragma unroll
        for (int q = 0; q < 2; ++q) {
            int idx = q * 512 + tid;
            kreg[q] = *(const f16x8*)(kb + (size_t)(mg0 + (idx >> 4)) * NC + (idx & 15) * 8);
            vreg[q] = *(const f16x8*)(vb + (size_t)(idx >> 3) * NS + mg0 + (idx & 7) * 8);
        }
    };
    auto store_kv = [&]() {
#pragma unroll
        for (int q = 0; q < 2; ++q) {
            int idx = q * 512 + tid;
            int r = idx >> 4, s = idx & 15;
            *(f16x8*)(Klds + r * 128 + ((s ^ (r & 7)) << 3)) = kreg[q];
            int rv = idx >> 3, sv = idx & 7;
            *(f16x8*)(Vlds + rv * 64 + ((sv ^ (rv & 7)) << 3)) = vreg[q];
        }
    };

    constexpr int NT = NS / 64;                   // 32 tiles: full m per block
    load_kv(0);
    for (int it = 0; it < NT; ++it) {
        const int mg0 = it * 64;
        const bool live = (mg0 < lenr);              // block-uniform
        __syncthreads();
        if (live) store_kv();
        if (it + 1 < NT) load_kv(mg0 + 64);
        __syncthreads();
        if (!live) {
            f32x4 z = {0.f, 0.f, 0.f, 0.f};
#pragma unroll
            for (int h = 0; h < 4; ++h)
                *(f32x4*)(attb + mg0 + h * 16 + 4 * g) = z;
            continue;
        }
#pragma unroll
        for (int half = 0; half < 2; ++half) {
            const int m0 = half * 32;
            f32x4 a0 = {0.f, 0.f, 0.f, 0.f}, a1 = {0.f, 0.f, 0.f, 0.f};
#pragma unroll
            for (int j = 0; j < 4; ++j) {
                f16x8 k0 = *(const f16x8*)(Klds + (m0 + ln) * 128 + ((((j << 2) + g) ^ swz) << 3));
                f16x8 k1 = *(const f16x8*)(Klds + (m0 + 16 + ln) * 128 + ((((j << 2) + g) ^ swz) << 3));
                a0 = MFMA16(k0, qf[j], a0);
                a1 = MFMA16(k1, qf[j], a1);
            }
            f32x4 p0, p1;
#pragma unroll
            for (int r = 0; r < 4; ++r) {
                int mi = mg0 + m0 + 4 * g + r;
                float v0 = (mi      < lenr) ? a0[r] * F_INV_TEMP : NEGBIG;
                float v1 = (mi + 16 < lenr) ? a1[r] * F_INV_TEMP : NEGBIG;
                p0[r] = __expf(v0 - M) * rinv;
                p1[r] = __expf(v1 - M) * rinv;
            }
            *(f32x4*)(attb + mg0 + m0 + 4 * g)      = p0;
            *(f32x4*)(attb + mg0 + m0 + 16 + 4 * g) = p1;

            f16x4 pk0, pk1;
#pragma unroll
            for (int r = 0; r < 4; ++r) {
                pk0[r] = (_Float16)p0[r];
                pk1[r] = (_Float16)p1[r];
            }
            *(f16x4*)&Plds[w][ln][4 * g]      = pk0;
            *(f16x4*)&Plds[w][ln][16 + 4 * g] = pk1;
            f16x8 pf = *(const f16x8*)&Plds[w][ln][g * 8];

#pragma unroll
            for (int ct = 0; ct < 8; ++ct) {
                f16x8 vf = *(const f16x8*)(Vlds + (ct * 16 + ln) * 64 +
                                           (((half * 4 + g) ^ swz) << 3));
                opv[ct] = MFMA16(pf, vf, opv[ct]);
            }
        }
    }

    // complete PV -> out0: plain stores (deterministic, no RMW)
    float* ob = out0 + (size_t)b * NC * NS;
#pragma unroll
    for (int ct = 0; ct < 8; ++ct)
        *(f32x4*)(ob + (size_t)(ct * 16 + ln) * NS + n_base + 4 * g) = opv[ct];
}

// ---------------- launch ----------------
extern "C" void kernel_launch(void* const* d_in, const int* in_sizes, int n_in,
                              void* d_out, int out_size, void* d_ws, size_t ws_size,
                              hipStream_t stream) {
    const float* xt   = (const float*)d_in[0];
    const float* xr   = (const float*)d_in[1];
    const int*   lmt  = (const int*)d_in[2];
    const int*   lmr  = (const int*)d_in[3];
    const float* xrgb = (const float*)d_in[6];
    const float* Wq   = (const float*)d_in[9];
    const float* bq   = (const float*)d_in[10];
    const float* Wk   = (const float*)d_in[11];
    const float* bk   = (const float*)d_in[12];
    const float* Wv   = (const float*)d_in[13];
    const float* bv   = (const float*)d_in[14];

    float* out0 = (float*)d_out;                       // [NB][NC][NS]
    float* att  = out0 + (size_t)NB * NC * NS;         // [NB][NS][NS]

    float* ws   = (float*)d_ws;
    int*   lens = (int*)d_ws;
    _Float16* h = (_Float16*)(ws + F16_OFF);
    _Float16* qt  = h + QT_H;
    _Float16* kt  = h + KT_H;
    _Float16* vt  = h + VT_H;
    _Float16* W16 = h + W16_H;

    k_lens<<<32, 256, 0, stream>>>(lmt, lmr, lens);
    k_prep<<<NC * NC / 256, 256, 0, stream>>>(Wq, Wk, Wv, W16);

    dim3 gproj(NS / 64, NB);
    k_qkv<true,  0><<<gproj, 256, 0, stream>>>(xt,   W16,               bq, qt, nullptr);
    k_qkv<true,  1><<<gproj, 256, 0, stream>>>(xr,   W16 + NC * NC,     bk, kt, nullptr);
    k_qkv<false, 2><<<gproj, 256, 0, stream>>>(xrgb, W16 + 2 * NC * NC, bv, nullptr, vt);

    dim3 gstats(NS / 128, CHA, NB);
    k_stats<<<gstats, 512, 0, stream>>>(qt, kt, lens, ws + PM_OFF, ws + PS_OFF);
    k_combine<<<(NB * NS) / 256, 256, 0, stream>>>(ws + PM_OFF, ws + PS_OFF, lens,
                                                   ws + RM_OFF, ws + RI_OFF);

    dim3 gattn(NS / 128, NB);
    k_attn2<<<gattn, 512, 0, stream>>>(qt, kt, vt, lens,
                                       ws + RM_OFF, ws + RI_OFF, att, out0);
}

// Round 14
// 165.229 us; speedup vs baseline: 3.4648x; 1.0004x over previous
//
#include <hip/hip_runtime.h>
#include <math.h>

constexpr int NB = 16;
constexpr int NC = 128;
constexpr int NS = 2048;          // Np1 == Mp1 == S
constexpr float F_INV_TEMP = 100.0f;
constexpr float F_EPS = 1e-5f;
constexpr float NEGBIG = -1e30f;

typedef __attribute__((ext_vector_type(8))) _Float16 f16x8;
typedef __attribute__((ext_vector_type(4))) _Float16 f16x4;
typedef __attribute__((ext_vector_type(4))) float f32x4;

#define MFMA16(a, b, c) __builtin_amdgcn_mfma_f32_16x16x32_f16((a), (b), (c), 0, 0, 0)

// ---- workspace layout ----
constexpr size_t F16_OFF = 64;                                // float offset of fp16 region
// fp16 region (element offsets):
constexpr size_t QT_H   = 0;                                  // q [b][s][c]
constexpr size_t KT_H   = QT_H + (size_t)NB * NS * NC;        // k [b][s][c]
constexpr size_t VT_H   = KT_H + (size_t)NB * NS * NC;        // v [b][c][s]
constexpr size_t W16_H  = VT_H + (size_t)NB * NS * NC;        // W16 [3][128][128]

// ---------------- K0: ragged lengths ----------------
__global__ void k_lens(const int* __restrict__ lm_t, const int* __restrict__ lm_r,
                       int* __restrict__ lens) {
    int b = blockIdx.x & 15;
    const int* src = (blockIdx.x < 16) ? lm_t : lm_r;
    src += b * 4096;
    int m = 0;
    for (int i = threadIdx.x; i < 4096; i += 256) m = max(m, src[i]);
    for (int off = 32; off; off >>= 1) m = max(m, __shfl_down(m, off, 64));
    __shared__ int red[4];
    if ((threadIdx.x & 63) == 0) red[threadIdx.x >> 6] = m;
    __syncthreads();
    if (threadIdx.x == 0) {
        m = max(max(red[0], red[1]), max(red[2], red[3]));
        lens[blockIdx.x] = m + 1;   // [0..15]=len_t, [16..31]=len_r
    }
}

// ---------------- K0b: convert W to fp16 ----------------
__global__ void k_prep(const float* __restrict__ Wq, const float* __restrict__ Wk,
                       const float* __restrict__ Wv, _Float16* __restrict__ W16) {
    int i = blockIdx.x * 256 + threadIdx.x;
    W16[i]               = (_Float16)Wq[i];
    W16[i + NC * NC]     = (_Float16)Wk[i];
    W16[i + 2 * NC * NC] = (_Float16)Wv[i];
}

// ---------------- K1: fused center-norm + projection GEMM (MFMA) ----------------
// MODE 0/1: out [b][s][c] fp16 (q,k); MODE 2: vout [b][c][s] fp16 (v)
template <bool NORM, int MODE>
__global__ __launch_bounds__(256) void k_qkv(const float* __restrict__ x,
                                             const _Float16* __restrict__ W16,
                                             const float* __restrict__ bias,
                                             _Float16* __restrict__ out,
                                             _Float16* __restrict__ vout) {
    __shared__ __align__(16) char smem[48 * 1024];
    float*    xs = (float*)smem;                        // [128][64] fp32 (32 KB)
    _Float16* xn = (_Float16*)(smem + 32 * 1024);       // [64][16 slots of 8] swizzled (16 KB)
    _Float16 (*Vt)[72] = (_Float16 (*)[72])smem;        // MODE2: [128][72] aliases xs
    __shared__ float ps[4][64], pq[4][64], cmean[64], cscale[64];

    const int b  = blockIdx.y;
    const int s0 = blockIdx.x * 64;
    const float* xb = x + (size_t)b * NC * NS + s0;

    for (int idx = threadIdx.x; idx < NC * 16; idx += 256) {
        int c = idx >> 4, j = (idx & 15) << 2;
        *(float4*)&xs[c * 64 + j] = *(const float4*)&xb[(size_t)c * NS + j];
    }
    __syncthreads();

    if (NORM) {
        int j = threadIdx.x & 63, p = threadIdx.x >> 6;
        float sum = 0.f, ssq = 0.f;
#pragma unroll
        for (int cc = 0; cc < 32; ++cc) {
            float v = xs[(p * 32 + cc) * 64 + j];
            sum += v; ssq += v * v;
        }
        ps[p][j] = sum; pq[p][j] = ssq;
        __syncthreads();
        if (threadIdx.x < 64) {
            float sm = ps[0][j] + ps[1][j] + ps[2][j] + ps[3][j];
            float sq = pq[0][j] + pq[1][j] + pq[2][j] + pq[3][j];
            float mean = sm * (1.f / NC);
            float var = sq - (float)NC * mean * mean;
            cmean[j]  = mean;
            cscale[j] = 1.f / (sqrtf(fmaxf(var, 0.f)) + F_EPS);
        }
        __syncthreads();
    }

    {
        const int lane = threadIdx.x & 63;           // s
        const int w4   = threadIdx.x >> 6;           // c chunk of 32
        const float mn = NORM ? cmean[lane] : 0.f;
        const float sc = NORM ? cscale[lane] : 1.f;
#pragma unroll
        for (int q = 0; q < 4; ++q) {
            f16x8 v8;
#pragma unroll
            for (int i = 0; i < 8; ++i)
                v8[i] = (_Float16)((xs[(w4 * 32 + q * 8 + i) * 64 + lane] - mn) * sc);
            *(f16x8*)(xn + lane * 128 + (((w4 * 4 + q) ^ (lane & 7)) << 3)) = v8;
        }
    }
    __syncthreads();   // xn ready; xs dead (Vt may alias it)

    const int w = threadIdx.x >> 6, lane = threadIdx.x & 63;
    const int ln = lane & 15, g = lane >> 4;
    const int sl = w * 16 + ln;                      // local s row (0..63)

    f16x8 xf[4];
#pragma unroll
    for (int jj = 0; jj < 4; ++jj)
        xf[jj] = *(const f16x8*)(xn + sl * 128 + (((jj * 4 + g) ^ (ln & 7)) << 3));

#pragma unroll
    for (int ot = 0; ot < 8; ++ot) {
        const _Float16* wrow = W16 + (size_t)(ot * 16 + ln) * NC + g * 8;
        f32x4 acc = {0.f, 0.f, 0.f, 0.f};
        acc = MFMA16(*(const f16x8*)(wrow),      xf[0], acc);
        acc = MFMA16(*(const f16x8*)(wrow + 32), xf[1], acc);
        acc = MFMA16(*(const f16x8*)(wrow + 64), xf[2], acc);
        acc = MFMA16(*(const f16x8*)(wrow + 96), xf[3], acc);
        const float4 bv = *(const float4*)&bias[ot * 16 + 4 * g];
        f16x4 res;
        res[0] = (_Float16)(acc[0] + bv.x);
        res[1] = (_Float16)(acc[1] + bv.y);
        res[2] = (_Float16)(acc[2] + bv.z);
        res[3] = (_Float16)(acc[3] + bv.w);
        if (MODE < 2) {
            *(f16x4*)(out + ((size_t)b * NS + s0 + sl) * NC + ot * 16 + 4 * g) = res;
        } else {
#pragma unroll
            for (int r = 0; r < 4; ++r)
                Vt[ot * 16 + 4 * g + r][sl] = res[r];
        }
    }
    if (MODE == 2) {
        __syncthreads();
        int o = threadIdx.x >> 1, sh = threadIdx.x & 1;
        _Float16* vr = vout + ((size_t)b * NC + o) * NS + s0 + sh * 32;
        const _Float16* src = &Vt[o][sh * 32];
#pragma unroll
        for (int i = 0; i < 4; ++i) *(f16x8*)(vr + i * 8) = *(const f16x8*)(src + i * 8);
    }
}

// ---------------- K5: fused attention (stats + recompute + att + PV, one kernel) ----
// Each block owns 128 n-rows x ALL m (CHB=1, r13: no atomics, no memset, no partials).
// Phase 1: online row max/sum over live K tiles (reg-dbuf K -> single LDS buffer).
// Phase 2: recompute QK^T, write att (trickled per-tile stores — r7-r9: never batch),
// accumulate PV, plain stores to out0. Fusion deletes k_stats+k_combine and the
// rM/rI global round-trip. r11: K LDS staging mandatory; r12: big blocks win.
__global__ __launch_bounds__(512, 4) void k_attn(const _Float16* __restrict__ qt,
                                                 const _Float16* __restrict__ kt,
                                                 const _Float16* __restrict__ vt,
                                                 const int* __restrict__ lens,
                                                 float* __restrict__ att,
                                                 float* __restrict__ out0) {
    __shared__ _Float16 Klds[64 * 128];
    __shared__ _Float16 Vlds[128 * 64];
    __shared__ _Float16 Plds[8][16][40];
    const int nt = blockIdx.x, b = blockIdx.y;
    const int tid = threadIdx.x;
    const int w = tid >> 6, lane = tid & 63, ln = lane & 15, g = lane >> 4;
    const int n_base = nt * 128 + w * 16;
    const int lenq = lens[b], lenr = lens[16 + b];
    const int swz = ln & 7;

    const _Float16* qrow = qt + ((size_t)b * NS + n_base + ln) * NC + g * 8;
    f16x8 qf[4];
#pragma unroll
    for (int j = 0; j < 4; ++j) qf[j] = *(const f16x8*)(qrow + 32 * j);

    const _Float16* kb = kt + (size_t)b * NS * NC;   // [m][c]
    const _Float16* vb = vt + (size_t)b * NC * NS;   // [c][m]

    f16x8 kreg[2], vreg[2];
    auto load_k = [&](int mg0) {
#pragma unroll
        for (int q = 0; q < 2; ++q) {
            int idx = q * 512 + tid;
            kreg[q] = *(const f16x8*)(kb + (size_t)(mg0 + (idx >> 4)) * NC + (idx & 15) * 8);
        }
    };
    auto store_k = [&]() {
#pragma unroll
        for (int q = 0; q < 2; ++q) {
            int idx = q * 512 + tid;
            int r = idx >> 4, s = idx & 15;
            *(f16x8*)(Klds + r * 128 + ((s ^ (r & 7)) << 3)) = kreg[q];
        }
    };
    auto load_v = [&](int mg0) {
#pragma unroll
        for (int q = 0; q < 2; ++q) {
            int idx = q * 512 + tid;
            vreg[q] = *(const f16x8*)(vb + (size_t)(idx >> 3) * NS + mg0 + (idx & 7) * 8);
        }
    };
    auto store_v = [&]() {
#pragma unroll
        for (int q = 0; q < 2; ++q) {
            int idx = q * 512 + tid;
            int rv = idx >> 3, sv = idx & 7;
            *(f16x8*)(Vlds + rv * 64 + ((sv ^ (rv & 7)) << 3)) = vreg[q];
        }
    };

    // ---------- phase 1: online row max / sum over live tiles ----------
    float mrun = NEGBIG, srun = 0.f;
    const int NT1 = (lenr + 63) >> 6;             // live tiles only (lenr >= 1)
    load_k(0);
    for (int it = 0; it < NT1; ++it) {
        const int mg0 = it * 64;
        __syncthreads();
        store_k();
        if (it + 1 < NT1) load_k(mg0 + 64);
        __syncthreads();
#pragma unroll
        for (int half = 0; half < 2; ++half) {
            const int m0 = half * 32;
            f32x4 a0 = {0.f, 0.f, 0.f, 0.f}, a1 = {0.f, 0.f, 0.f, 0.f};
#pragma unroll
            for (int j = 0; j < 4; ++j) {
                f16x8 k0 = *(const f16x8*)(Klds + (m0 + ln) * 128 + ((((j << 2) + g) ^ swz) << 3));
                f16x8 k1 = *(const f16x8*)(Klds + (m0 + 16 + ln) * 128 + ((((j << 2) + g) ^ swz) << 3));
                a0 = MFMA16(k0, qf[j], a0);
                a1 = MFMA16(k1, qf[j], a1);
            }
            float vv[8];
#pragma unroll
            for (int r = 0; r < 4; ++r) {
                int mi = mg0 + m0 + 4 * g + r;
                vv[r]     = (mi      < lenr) ? a0[r] * F_INV_TEMP : NEGBIG;
                vv[4 + r] = (mi + 16 < lenr) ? a1[r] * F_INV_TEMP : NEGBIG;
            }
            float cmax = fmaxf(fmaxf(fmaxf(vv[0], vv[1]), fmaxf(vv[2], vv[3])),
                               fmaxf(fmaxf(vv[4], vv[5]), fmaxf(vv[6], vv[7])));
            float newm = fmaxf(mrun, cmax);
            float ssum = 0.f;
#pragma unroll
            for (int i = 0; i < 8; ++i) ssum += __expf(vv[i] - newm);
            srun = srun * __expf(mrun - newm) + ssum;
            mrun = newm;
        }
    }
    // reduce across the 4 row-groups (lanes l^16, l^32 share the same n)
#pragma unroll
    for (int off = 16; off <= 32; off <<= 1) {
        float om = __shfl_xor(mrun, off, 64);
        float os = __shfl_xor(srun, off, 64);
        float nm = fmaxf(mrun, om);
        srun = srun * __expf(mrun - nm) + os * __expf(om - nm);
        mrun = nm;
    }
    const float M = mrun;
    const float rinv = ((n_base + ln) < lenq) ? (1.0f / srun) : 0.0f;

    // ---------- phase 2: recompute, write att, accumulate PV ----------
    f32x4 opv[8];
#pragma unroll
    for (int ct = 0; ct < 8; ++ct) opv[ct] = f32x4{0.f, 0.f, 0.f, 0.f};

    float* attb = att + ((size_t)b * NS + n_base + ln) * NS;

    constexpr int NT = NS / 64;                   // 32 tiles: full m per block
    load_k(0); load_v(0);
    for (int it = 0; it < NT; ++it) {
        const int mg0 = it * 64;
        const bool live = (mg0 < lenr);              // block-uniform
        __syncthreads();
        if (live) { store_k(); store_v(); }
        if (it + 1 < NT) { load_k(mg0 + 64); load_v(mg0 + 64); }
        __syncthreads();
        if (!live) {
            f32x4 z = {0.f, 0.f, 0.f, 0.f};
#pragma unroll
            for (int h = 0; h < 4; ++h)
                *(f32x4*)(attb + mg0 + h * 16 + 4 * g) = z;
            continue;
        }
#pragma unroll
        for (int half = 0; half < 2; ++half) {
            const int m0 = half * 32;
            f32x4 a0 = {0.f, 0.f, 0.f, 0.f}, a1 = {0.f, 0.f, 0.f, 0.f};
#pragma unroll
            for (int j = 0; j < 4; ++j) {
                f16x8 k0 = *(const f16x8*)(Klds + (m0 + ln) * 128 + ((((j << 2) + g) ^ swz) << 3));
                f16x8 k1 = *(const f16x8*)(Klds + (m0 + 16 + ln) * 128 + ((((j << 2) + g) ^ swz) << 3));
                a0 = MFMA16(k0, qf[j], a0);
                a1 = MFMA16(k1, qf[j], a1);
            }
            f32x4 p0, p1;
#pragma unroll
            for (int r = 0; r < 4; ++r) {
                int mi = mg0 + m0 + 4 * g + r;
                float v0 = (mi      < lenr) ? a0[r] * F_INV_TEMP : NEGBIG;
                float v1 = (mi + 16 < lenr) ? a1[r] * F_INV_TEMP : NEGBIG;
                p0[r] = __expf(v0 - M) * rinv;    // masked -> exactly 0
                p1[r] = __expf(v1 - M) * rinv;
            }
            *(f32x4*)(attb + mg0 + m0 + 4 * g)      = p0;
            *(f32x4*)(attb + mg0 + m0 + 16 + 4 * g) = p1;

            f16x4 pk0, pk1;
#pragma unroll
            for (int r = 0; r < 4; ++r) {
                pk0[r] = (_Float16)p0[r];
                pk1[r] = (_Float16)p1[r];
            }
            *(f16x4*)&Plds[w][ln][4 * g]      = pk0;
            *(f16x4*)&Plds[w][ln][16 + 4 * g] = pk1;
            f16x8 pf = *(const f16x8*)&Plds[w][ln][g * 8];

#pragma unroll
            for (int ct = 0; ct < 8; ++ct) {
                f16x8 vf = *(const f16x8*)(Vlds + (ct * 16 + ln) * 64 +
                                           (((half * 4 + g) ^ swz) << 3));
                opv[ct] = MFMA16(pf, vf, opv[ct]);
            }
        }
    }

    // complete PV -> out0: plain stores (deterministic, no RMW)
    float* ob = out0 + (size_t)b * NC * NS;
#pragma unroll
    for (int ct = 0; ct < 8; ++ct)
        *(f32x4*)(ob + (size_t)(ct * 16 + ln) * NS + n_base + 4 * g) = opv[ct];
}

// ---------------- launch ----------------
extern "C" void kernel_launch(void* const* d_in, const int* in_sizes, int n_in,
                              void* d_out, int out_size, void* d_ws, size_t ws_size,
                              hipStream_t stream) {
    const float* xt   = (const float*)d_in[0];
    const float* xr   = (const float*)d_in[1];
    const int*   lmt  = (const int*)d_in[2];
    const int*   lmr  = (const int*)d_in[3];
    const float* xrgb = (const float*)d_in[6];
    const float* Wq   = (const float*)d_in[9];
    const float* bq   = (const float*)d_in[10];
    const float* Wk   = (const float*)d_in[11];
    const float* bk   = (const float*)d_in[12];
    const float* Wv   = (const float*)d_in[13];
    const float* bv   = (const float*)d_in[14];

    float* out0 = (float*)d_out;                       // [NB][NC][NS]
    float* att  = out0 + (size_t)NB * NC * NS;         // [NB][NS][NS]

    float* ws   = (float*)d_ws;
    int*   lens = (int*)d_ws;
    _Float16* h = (_Float16*)(ws + F16_OFF);
    _Float16* qt  = h + QT_H;
    _Float16* kt  = h + KT_H;
    _Float16* vt  = h + VT_H;
    _Float16* W16 = h + W16_H;

    k_lens<<<32, 256, 0, stream>>>(lmt, lmr, lens);
    k_prep<<<NC * NC / 256, 256, 0, stream>>>(Wq, Wk, Wv, W16);

    dim3 gproj(NS / 64, NB);
    k_qkv<true,  0><<<gproj, 256, 0, stream>>>(xt,   W16,               bq, qt, nullptr);
    k_qkv<true,  1><<<gproj, 256, 0, stream>>>(xr,   W16 + NC * NC,     bk, kt, nullptr);
    k_qkv<false, 2><<<gproj, 256, 0, stream>>>(xrgb, W16 + 2 * NC * NC, bv, nullptr, vt);

    dim3 gattn(NS / 128, NB);
    k_attn<<<gattn, 512, 0, stream>>>(qt, kt, vt, lens, att, out0);
}